// Round 5
// baseline (268.791 us; speedup 1.0000x reference)
//
#include <hip/hip_runtime.h>

// ---------------------------------------------------------------------------
// Edge-conditioned kernel MLP, fully fused. R5: flipped orientation —
// C = mfma(A=W from L2/regs, B=edges/h from LDS). No W LDS tile, no barriers.
// Wave = 32 edge-cols; LN + GEMV reduce over hi lanes (2 shfls). fp32
// post-GEMM path (R4-verified numerics: bias/LN/erff-GELU/GEMV all fp32).
// ---------------------------------------------------------------------------

typedef __bf16 bf16x8 __attribute__((ext_vector_type(8)));
typedef float f32x4 __attribute__((ext_vector_type(4)));
typedef unsigned short ushort8 __attribute__((ext_vector_type(8)));
typedef unsigned short ushort4v __attribute__((ext_vector_type(4)));

#define N_EDGES 147456
#define TM 128            // edges per block = 4 waves x 32

__device__ __forceinline__ unsigned short f2bf(float f) {
    unsigned u = __float_as_uint(f);
    u = u + 0x7FFFu + ((u >> 16) & 1u);   // RNE
    return (unsigned short)(u >> 16);
}

// Prep (R1 verbatim): W1,W2 (128x128), W3 (128x1024) fp32 -> bf16 W^T [n][k].
__global__ void prep_weights(const float* __restrict__ W1,
                             const float* __restrict__ W2,
                             const float* __restrict__ W3,
                             unsigned short* __restrict__ ws) {
    int t = blockIdx.x * 256 + threadIdx.x;          // 163840 total
    if (t < 16384) {
        int k = t >> 7, n = t & 127;
        ws[n * 128 + k] = f2bf(W1[t]);
    } else if (t < 32768) {
        int j = t - 16384;
        int k = j >> 7, n = j & 127;
        ws[16384 + n * 128 + k] = f2bf(W2[j]);
    } else {
        int j = t - 32768;                           // j = k*1024 + n
        int k = j >> 10, n = j & 1023;
        int tile = n >> 7, nl = n & 127;
        ws[32768 + tile * 16384 + nl * 128 + k] = f2bf(W3[j]);
    }
}

__global__ __launch_bounds__(256, 3)
void fused_edge_mlp(const float* __restrict__ edge, const float* __restrict__ x,
                    const float* __restrict__ b1, const float* __restrict__ g1,
                    const float* __restrict__ be1,
                    const float* __restrict__ b2, const float* __restrict__ g2,
                    const float* __restrict__ be2,
                    const float* __restrict__ b3,
                    const unsigned short* __restrict__ wsW,
                    float* __restrict__ out) {
    // sA: bf16 [128 edge-rows][128 k], 256B/row, XOR-swizzled (slot ^ (row&7)).
    // Holds edge, then h1, then h2. Rows are wave-private -> NO barriers.
    __shared__ __align__(16) unsigned char sA[TM * 256];       // 32 KB

    const int t    = threadIdx.x;
    const int lane = t & 63;
    const int w    = t >> 6;
    const int e0   = blockIdx.x * TM;
    const int erow = w * 32;          // wave's first local edge row
    const int mrow = lane & 15;
    const int hi   = lane >> 4;
    const int swzl = (mrow & 7) << 4;

    // ---- stage edge rows (wave-own, coalesced: 4 rows x 512B per iter) ----
#pragma unroll
    for (int i = 0; i < 8; i++) {
        int c = lane + i * 64;                       // 512 chunks of 8 floats
        int r = erow + (c >> 4), kg = c & 15;
        const float* src = edge + (size_t)(e0 + r) * 128 + kg * 8;
        float4 v0 = *(const float4*)src, v1 = *(const float4*)(src + 4);
        ushort8 u;
        u[0] = f2bf(v0.x); u[1] = f2bf(v0.y); u[2] = f2bf(v0.z); u[3] = f2bf(v0.w);
        u[4] = f2bf(v1.x); u[5] = f2bf(v1.y); u[6] = f2bf(v1.z); u[7] = f2bf(v1.w);
        *(ushort8*)(sA + r * 256 + ((kg * 16) ^ ((r & 7) << 4))) = u;
    }

    // ---- x -> fp32 regs: xq[fe][b][rr] = x[edge(fe)][b*16 + hi*4 + rr] ----
    f32x4 xq[2][2];
#pragma unroll
    for (int fe = 0; fe < 2; fe++)
#pragma unroll
        for (int b = 0; b < 2; b++)
            xq[fe][b] = *(const f32x4*)(
                x + (size_t)(e0 + erow + fe * 16 + mrow) * 32 + b * 16 + hi * 4);

    // ---- MFMA pass: C[n=128][e=32] += W(L2)^T . h(LDS), K=128 ----
    // A-frag: lane row n = fn*16+mrow, k = kk*32+hi*8 (linear read from ws).
    // B-frag: lane col e = erow+fe*16+mrow, same k from sA (swizzled).
    auto runMM = [&](f32x4 (&acc)[2][8], const unsigned short* wA) {
#pragma unroll
        for (int kk = 0; kk < 4; kk++) {
            int kb = (kk * 64 + hi * 16) ^ swzl;
            bf16x8 bA = *(const bf16x8*)(sA + (erow + mrow) * 256 + kb);
            bf16x8 bB = *(const bf16x8*)(sA + (erow + 16 + mrow) * 256 + kb);
#pragma unroll
            for (int fn = 0; fn < 8; fn++) {
                bf16x8 a = *(const bf16x8*)(wA + (fn * 16 + mrow) * 128 + kk * 32 + hi * 8);
                acc[0][fn] = __builtin_amdgcn_mfma_f32_16x16x32_bf16(a, bA, acc[0][fn], 0, 0, 0);
                acc[1][fn] = __builtin_amdgcn_mfma_f32_16x16x32_bf16(a, bB, acc[1][fn], 0, 0, 0);
            }
        }
    };
    // C/D: col(e-local-16) = mrow, row n = fn*16 + hi*4 + rr.

    // ---- LN + exact GELU per edge-col; h -> own sA row (b64-packed) ----
    auto lnGelu = [&](f32x4 (&acc)[2][8], const float* bb, const float* gg,
                      const float* ee) {
#pragma unroll
        for (int fe = 0; fe < 2; fe++) {
            float hv[8][4];
            float s = 0.f, s2 = 0.f;
#pragma unroll
            for (int fn = 0; fn < 8; fn++) {
                f32x4 b4 = *(const f32x4*)(bb + fn * 16 + hi * 4);
#pragma unroll
                for (int rr = 0; rr < 4; rr++) {
                    float v = acc[fe][fn][rr] + b4[rr];
                    hv[fn][rr] = v; s += v; s2 += v * v;
                }
            }
            s  += __shfl_xor(s, 16);  s  += __shfl_xor(s, 32);
            s2 += __shfl_xor(s2, 16); s2 += __shfl_xor(s2, 32);
            float mean = s * (1.0f / 128.0f);
            float rsv  = rsqrtf(s2 * (1.0f / 128.0f) - mean * mean + 1e-5f);
            int row = erow + fe * 16 + mrow;         // row&7 == mrow&7
#pragma unroll
            for (int fn = 0; fn < 8; fn++) {
                f32x4 g4 = *(const f32x4*)(gg + fn * 16 + hi * 4);
                f32x4 e4 = *(const f32x4*)(ee + fn * 16 + hi * 4);
                ushort4v u;
#pragma unroll
                for (int rr = 0; rr < 4; rr++) {
                    float f = (hv[fn][rr] - mean) * rsv * g4[rr] + e4[rr];
                    f = 0.5f * f * (1.0f + erff(f * 0.70710678118f));   // exact GELU
                    u[rr] = f2bf(f);
                }
                // feature n = fn*16 + hi*4 + rr -> bytes fn*32 + hi*8 + rr*2
                *(ushort4v*)(sA + row * 256 + ((fn * 32 + hi * 8) ^ swzl)) = u;
            }
        }
    };

    // ---- layer-3 GEMV: out[e, c*4+o] = sum_n (k[n,e]+b3[n]) * x[e, n&31] ----
    auto gemv = [&](f32x4 (&acc)[2][8], int c) {
        f32x4 b3q[8];
#pragma unroll
        for (int fn = 0; fn < 8; fn++)
            b3q[fn] = *(const f32x4*)(b3 + c * 128 + fn * 16 + hi * 4);
#pragma unroll
        for (int fe = 0; fe < 2; fe++) {
#pragma unroll
            for (int o = 0; o < 4; o++) {
                float p = 0.f;
#pragma unroll
                for (int rr = 0; rr < 4; rr++) {
                    p += (acc[fe][2*o][rr]   + b3q[2*o][rr])   * xq[fe][0][rr];
                    p += (acc[fe][2*o+1][rr] + b3q[2*o+1][rr]) * xq[fe][1][rr];
                }
                p += __shfl_xor(p, 16);              // reduce over hi
                p += __shfl_xor(p, 32);
                if (hi == o)
                    out[(size_t)(e0 + erow + fe * 16 + mrow) * 32 + c * 4 + o] = p;
            }
        }
    };

    f32x4 acc[2][8];
    const f32x4 zz = {0.f, 0.f, 0.f, 0.f};

    // layer 1
#pragma unroll
    for (int i = 0; i < 2; i++) for (int j = 0; j < 8; j++) acc[i][j] = zz;
    runMM(acc, wsW);
    lnGelu(acc, b1, g1, be1);
    // layer 2
#pragma unroll
    for (int i = 0; i < 2; i++) for (int j = 0; j < 8; j++) acc[i][j] = zz;
    runMM(acc, wsW + 16384);
    lnGelu(acc, b2, g2, be2);
    // layer 3: 8 chunks of 128 features + fused GEMV
    for (int c = 0; c < 8; c++) {
#pragma unroll
        for (int i = 0; i < 2; i++) for (int j = 0; j < 8; j++) acc[i][j] = zz;
        runMM(acc, wsW + 32768 + c * 16384);
        gemv(acc, c);
    }
}

extern "C" void kernel_launch(void* const* d_in, const int* in_sizes, int n_in,
                              void* d_out, int out_size, void* d_ws, size_t ws_size,
                              hipStream_t stream) {
    const float* x    = (const float*)d_in[0];
    const float* edge = (const float*)d_in[1];
    const float* W1   = (const float*)d_in[2];
    const float* b1   = (const float*)d_in[3];
    const float* g1   = (const float*)d_in[4];
    const float* be1  = (const float*)d_in[5];
    const float* W2   = (const float*)d_in[6];
    const float* b2   = (const float*)d_in[7];
    const float* g2   = (const float*)d_in[8];
    const float* be2  = (const float*)d_in[9];
    const float* W3   = (const float*)d_in[10];
    const float* b3   = (const float*)d_in[11];
    unsigned short* wsW = (unsigned short*)d_ws;     // 320 KB: W1^T|W2^T|W3^T bf16
    float* outp = (float*)d_out;

    prep_weights<<<640, 256, 0, stream>>>(W1, W2, W3, wsW);
    fused_edge_mlp<<<N_EDGES / TM, 256, 0, stream>>>(
        edge, x, b1, g1, be1, b2, g2, be2, b3, wsW, outp);
}

// Round 6
// 215.057 us; speedup vs baseline: 1.2499x; 1.2499x over previous
//
#include <hip/hip_runtime.h>

// ---------------------------------------------------------------------------
// Edge-conditioned kernel MLP, fully fused. R6 = R5 flipped orientation
// (C = W·h, cheap hi-lane reductions — verified) + W staged in LDS per block
// (R4's verified stageB pattern, loads issued early to hide L2 latency) +
// register-cached h2 B-frags across layer-3 chunks + batched float4 output
// stores (kills the 4x writeback amplification seen in R4/R5).
// ---------------------------------------------------------------------------

typedef __bf16 bf16x8 __attribute__((ext_vector_type(8)));
typedef float f32x4 __attribute__((ext_vector_type(4)));
typedef unsigned short ushort8 __attribute__((ext_vector_type(8)));
typedef unsigned short ushort4v __attribute__((ext_vector_type(4)));

#define N_EDGES 147456
#define TM 128            // edges per block = 4 waves x 32

__device__ __forceinline__ unsigned short f2bf(float f) {
    unsigned u = __float_as_uint(f);
    u = u + 0x7FFFu + ((u >> 16) & 1u);   // RNE
    return (unsigned short)(u >> 16);
}

// Prep (R5 verbatim, verified): W1,W2 (128x128), W3 (128x1024) -> bf16 W^T
// [n][k]; W3 tiled per 128-col chunk.
__global__ void prep_weights(const float* __restrict__ W1,
                             const float* __restrict__ W2,
                             const float* __restrict__ W3,
                             unsigned short* __restrict__ ws) {
    int t = blockIdx.x * 256 + threadIdx.x;          // 163840 total
    if (t < 16384) {
        int k = t >> 7, n = t & 127;
        ws[n * 128 + k] = f2bf(W1[t]);
    } else if (t < 32768) {
        int j = t - 16384;
        int k = j >> 7, n = j & 127;
        ws[16384 + n * 128 + k] = f2bf(W2[j]);
    } else {
        int j = t - 32768;                           // j = k*1024 + n
        int k = j >> 10, n = j & 1023;
        int tile = n >> 7, nl = n & 127;
        ws[32768 + tile * 16384 + nl * 128 + k] = f2bf(W3[j]);
    }
}

__global__ __launch_bounds__(256, 2)
void fused_edge_mlp(const float* __restrict__ edge, const float* __restrict__ x,
                    const float* __restrict__ b1, const float* __restrict__ g1,
                    const float* __restrict__ be1,
                    const float* __restrict__ b2, const float* __restrict__ g2,
                    const float* __restrict__ be2,
                    const float* __restrict__ b3,
                    const unsigned short* __restrict__ wsW,
                    float* __restrict__ out) {
    // sA: bf16 [128 edge-rows][128 k], 256B/row, XOR-swizzled. edge->h1->h2.
    // Rows are wave-private (each wave only touches its own 32 rows).
    __shared__ __align__(16) unsigned char sA[TM * 256];       // 32 KB
    // sW: bf16 W^T tile [128 n][128 k], same swizzle. Shared -> barriers.
    __shared__ __align__(16) unsigned char sW[128 * 256];      // 32 KB

    const int t    = threadIdx.x;
    const int lane = t & 63;
    const int w    = t >> 6;
    const int e0   = blockIdx.x * TM;
    const int erow = w * 32;          // wave's first local edge row
    const int mrow = lane & 15;
    const int hi   = lane >> 4;
    const int swzl = (mrow & 7) << 4;

    // ---- W staging, split so global loads issue early (latency hiding) ----
    uint4 wpre[8];
    auto loadW = [&](const unsigned short* srcW) {
#pragma unroll
        for (int i = 0; i < 8; i++) {
            int cid = t + i * 256;            // 2048 x 16B chunks
            int r = cid >> 4, kg = cid & 15;
            wpre[i] = *(const uint4*)(srcW + r * 128 + kg * 8);
        }
    };
    auto writeW = [&]() {
#pragma unroll
        for (int i = 0; i < 8; i++) {
            int cid = t + i * 256;
            int r = cid >> 4, kg = cid & 15;
            *(uint4*)(sW + r * 256 + ((kg * 16) ^ ((r & 7) << 4))) = wpre[i];
        }
    };

    // ---- MFMA pass (layers 1/2): C[n=128][e=32] += W(sW)^T . h(sA) ----
    auto runMM = [&](f32x4 (&acc)[2][8]) {
#pragma unroll
        for (int kk = 0; kk < 4; kk++) {
            int kb = (kk * 64 + hi * 16) ^ swzl;
            bf16x8 bA = *(const bf16x8*)(sA + (erow + mrow) * 256 + kb);
            bf16x8 bB = *(const bf16x8*)(sA + (erow + 16 + mrow) * 256 + kb);
#pragma unroll
            for (int fn = 0; fn < 8; fn++) {
                bf16x8 a = *(const bf16x8*)(sW + (fn * 16 + mrow) * 256 + kb);
                acc[0][fn] = __builtin_amdgcn_mfma_f32_16x16x32_bf16(a, bA, acc[0][fn], 0, 0, 0);
                acc[1][fn] = __builtin_amdgcn_mfma_f32_16x16x32_bf16(a, bB, acc[1][fn], 0, 0, 0);
            }
        }
    };
    // C/D: col(e-local-16) = mrow, feature n = fn*16 + hi*4 + rr.

    // ---- layer-3 MFMA with h2 B-frags cached in registers ----
    auto runMM3 = [&](f32x4 (&acc)[2][8], const bf16x8 (&bc)[2][4]) {
#pragma unroll
        for (int kk = 0; kk < 4; kk++) {
            int kb = (kk * 64 + hi * 16) ^ swzl;
#pragma unroll
            for (int fn = 0; fn < 8; fn++) {
                bf16x8 a = *(const bf16x8*)(sW + (fn * 16 + mrow) * 256 + kb);
                acc[0][fn] = __builtin_amdgcn_mfma_f32_16x16x32_bf16(a, bc[0][kk], acc[0][fn], 0, 0, 0);
                acc[1][fn] = __builtin_amdgcn_mfma_f32_16x16x32_bf16(a, bc[1][kk], acc[1][fn], 0, 0, 0);
            }
        }
    };

    // ---- x -> fp32 regs (R5 verbatim) ----
    f32x4 xq[2][2];

    // ---- LN + exact GELU per edge-col (R5 verbatim, verified) ----
    auto lnGelu = [&](f32x4 (&acc)[2][8], const float* bb, const float* gg,
                      const float* ee) {
#pragma unroll
        for (int fe = 0; fe < 2; fe++) {
            float hv[8][4];
            float s = 0.f, s2 = 0.f;
#pragma unroll
            for (int fn = 0; fn < 8; fn++) {
                f32x4 b4 = *(const f32x4*)(bb + fn * 16 + hi * 4);
#pragma unroll
                for (int rr = 0; rr < 4; rr++) {
                    float v = acc[fe][fn][rr] + b4[rr];
                    hv[fn][rr] = v; s += v; s2 += v * v;
                }
            }
            s  += __shfl_xor(s, 16);  s  += __shfl_xor(s, 32);
            s2 += __shfl_xor(s2, 16); s2 += __shfl_xor(s2, 32);
            float mean = s * (1.0f / 128.0f);
            float rsv  = rsqrtf(s2 * (1.0f / 128.0f) - mean * mean + 1e-5f);
            int row = erow + fe * 16 + mrow;         // row&7 == mrow&7
#pragma unroll
            for (int fn = 0; fn < 8; fn++) {
                f32x4 g4 = *(const f32x4*)(gg + fn * 16 + hi * 4);
                f32x4 e4 = *(const f32x4*)(ee + fn * 16 + hi * 4);
                ushort4v u;
#pragma unroll
                for (int rr = 0; rr < 4; rr++) {
                    float f = (hv[fn][rr] - mean) * rsv * g4[rr] + e4[rr];
                    f = 0.5f * f * (1.0f + erff(f * 0.70710678118f));   // exact GELU
                    u[rr] = f2bf(f);
                }
                *(ushort4v*)(sA + row * 256 + ((fn * 32 + hi * 8) ^ swzl)) = u;
            }
        }
    };

    // ---- layer-3 GEMV into register vout (R5 math, batched store later) ----
    // out[e, c*4+o] with o' = fn>>1; lane hi retains chunks {2hi, 2hi+1}.
    f32x4 vout[2][2];
    auto gemv = [&](f32x4 (&acc)[2][8], int c) {
        f32x4 b3q[8];
#pragma unroll
        for (int fn = 0; fn < 8; fn++)
            b3q[fn] = *(const f32x4*)(b3 + c * 128 + fn * 16 + hi * 4);
#pragma unroll
        for (int fe = 0; fe < 2; fe++) {
#pragma unroll
            for (int o = 0; o < 4; o++) {
                float p = 0.f;
#pragma unroll
                for (int rr = 0; rr < 4; rr++) {
                    p += (acc[fe][2*o][rr]   + b3q[2*o][rr])   * xq[fe][0][rr];
                    p += (acc[fe][2*o+1][rr] + b3q[2*o+1][rr]) * xq[fe][1][rr];
                }
                p += __shfl_xor(p, 16);              // reduce over hi
                p += __shfl_xor(p, 32);
                if ((c >> 1) == hi) vout[fe][c & 1][o] = p;   // c const-folded
            }
        }
    };

    // ================= prologue =================
#pragma unroll
    for (int i = 0; i < 8; i++) {                    // edge -> sA (R5 verbatim)
        int c = lane + i * 64;                       // 512 chunks of 8 floats
        int r = erow + (c >> 4), kg = c & 15;
        const float* src = edge + (size_t)(e0 + r) * 128 + kg * 8;
        float4 v0 = *(const float4*)src, v1 = *(const float4*)(src + 4);
        ushort8 u;
        u[0] = f2bf(v0.x); u[1] = f2bf(v0.y); u[2] = f2bf(v0.z); u[3] = f2bf(v0.w);
        u[4] = f2bf(v1.x); u[5] = f2bf(v1.y); u[6] = f2bf(v1.z); u[7] = f2bf(v1.w);
        *(ushort8*)(sA + r * 256 + ((kg * 16) ^ ((r & 7) << 4))) = u;
    }
#pragma unroll
    for (int fe = 0; fe < 2; fe++)
#pragma unroll
        for (int b = 0; b < 2; b++)
            xq[fe][b] = *(const f32x4*)(
                x + (size_t)(e0 + erow + fe * 16 + mrow) * 32 + b * 16 + hi * 4);
    loadW(wsW); writeW();                            // W1 -> sW
    __syncthreads();

    f32x4 acc[2][8];
    const f32x4 zz = {0.f, 0.f, 0.f, 0.f};

    // ================= layer 1 =================
#pragma unroll
    for (int i = 0; i < 2; i++) for (int j = 0; j < 8; j++) acc[i][j] = zz;
    runMM(acc);                       // reads sW(W1) + own sA rows
    __syncthreads();                  // all waves done reading sW(W1)
    loadW(wsW + 16384);               // W2 global loads (overlap lnGelu)
    lnGelu(acc, b1, g1, be1);         // own sA rows <- h1
    writeW();                         // W2 -> sW
    __syncthreads();

    // ================= layer 2 =================
#pragma unroll
    for (int i = 0; i < 2; i++) for (int j = 0; j < 8; j++) acc[i][j] = zz;
    runMM(acc);
    __syncthreads();
    loadW(wsW + 32768);               // W3 chunk 0
    lnGelu(acc, b2, g2, be2);         // own sA rows <- h2
    writeW();
    __syncthreads();

    // ---- cache h2 B-frags in registers (sA never written again) ----
    bf16x8 bc[2][4];
#pragma unroll
    for (int kk = 0; kk < 4; kk++) {
        int kb = (kk * 64 + hi * 16) ^ swzl;
        bc[0][kk] = *(const bf16x8*)(sA + (erow + mrow) * 256 + kb);
        bc[1][kk] = *(const bf16x8*)(sA + (erow + 16 + mrow) * 256 + kb);
    }

    // ================= layer 3: 8 chunks of 128 features =================
#pragma unroll
    for (int c = 0; c < 8; c++) {
#pragma unroll
        for (int i = 0; i < 2; i++) for (int j = 0; j < 8; j++) acc[i][j] = zz;
        runMM3(acc, bc);              // reads sW(W3c) + bc regs
        if (c < 7) {
            __syncthreads();          // sW(W3c) reads done
            loadW(wsW + 32768 + (size_t)(c + 1) * 16384);
            gemv(acc, c);             // VALU+shfl under load latency
            writeW();
            __syncthreads();
        } else {
            gemv(acc, c);
        }
    }

    // ================= batched output store (full rows, no amplification) ====
#pragma unroll
    for (int fe = 0; fe < 2; fe++) {
        size_t e = (size_t)(e0 + erow + fe * 16 + mrow);
        *(f32x4*)(out + e * 32 + hi * 8)     = vout[fe][0];
        *(f32x4*)(out + e * 32 + hi * 8 + 4) = vout[fe][1];
    }
}

extern "C" void kernel_launch(void* const* d_in, const int* in_sizes, int n_in,
                              void* d_out, int out_size, void* d_ws, size_t ws_size,
                              hipStream_t stream) {
    const float* x    = (const float*)d_in[0];
    const float* edge = (const float*)d_in[1];
    const float* W1   = (const float*)d_in[2];
    const float* b1   = (const float*)d_in[3];
    const float* g1   = (const float*)d_in[4];
    const float* be1  = (const float*)d_in[5];
    const float* W2   = (const float*)d_in[6];
    const float* b2   = (const float*)d_in[7];
    const float* g2   = (const float*)d_in[8];
    const float* be2  = (const float*)d_in[9];
    const float* W3   = (const float*)d_in[10];
    const float* b3   = (const float*)d_in[11];
    unsigned short* wsW = (unsigned short*)d_ws;     // 320 KB: W1^T|W2^T|W3^T bf16
    float* outp = (float*)d_out;

    prep_weights<<<640, 256, 0, stream>>>(W1, W2, W3, wsW);
    fused_edge_mlp<<<N_EDGES / TM, 256, 0, stream>>>(
        edge, x, b1, g1, be1, b2, g2, be2, b3, wsW, outp);
}

// Round 7
// 143.551 us; speedup vs baseline: 1.8724x; 1.4981x over previous
//
#include <hip/hip_runtime.h>

// ---------------------------------------------------------------------------
// Edge-conditioned kernel MLP, fully fused. R7 = R6 structure (flipped
// orientation C = W·h, verified) with the two register hogs removed:
//   - W staged via global_load_lds (width 16) from PRE-SWIZZLED workspace
//     (no wpre regs, no ds_write; content == R6's verified writeW layout)
//   - layer-3 outputs staged in LDS (sA reused as sOut[128][36] fp32) with
//     aligned f32x4 writes; epilogue does coalesced 16B global stores.
// All register arrays statically indexed; live set ~160 VGPR -> no spill.
// ---------------------------------------------------------------------------

typedef __bf16 bf16x8 __attribute__((ext_vector_type(8)));
typedef float f32x4 __attribute__((ext_vector_type(4)));
typedef unsigned short ushort8 __attribute__((ext_vector_type(8)));
typedef unsigned short ushort4v __attribute__((ext_vector_type(4)));

#define N_EDGES 147456
#define TM 128            // edges per block = 4 waves x 32
#define OPITCH 36         // sOut fp32 pitch: 144 B = 9*16 (aligned, bank-spread)

__device__ __forceinline__ unsigned short f2bf(float f) {
    unsigned u = __float_as_uint(f);
    u = u + 0x7FFFu + ((u >> 16) & 1u);   // RNE
    return (unsigned short)(u >> 16);
}
__device__ __forceinline__ void gl_lds16(const unsigned short* g, unsigned char* l) {
    __builtin_amdgcn_global_load_lds(
        (const __attribute__((address_space(1))) unsigned int*)g,
        (__attribute__((address_space(3))) unsigned int*)l, 16, 0, 0);
}

// Prep: W^T bf16, PRE-SWIZZLED so linear-dest global_load_lds yields exactly
// R6's verified LDS layout: slot s at row n holds chunk (s ^ (n&7)).
// Element (n, k) -> ws[n*128 + (((k>>3)^(n&7))<<3) + (k&7)].
__global__ void prep_weights(const float* __restrict__ W1,
                             const float* __restrict__ W2,
                             const float* __restrict__ W3,
                             unsigned short* __restrict__ ws) {
    int t = blockIdx.x * 256 + threadIdx.x;          // 163840 total
    if (t < 16384) {
        int k = t >> 7, n = t & 127;
        ws[n * 128 + (((k >> 3) ^ (n & 7)) << 3) + (k & 7)] = f2bf(W1[t]);
    } else if (t < 32768) {
        int j = t - 16384;
        int k = j >> 7, n = j & 127;
        ws[16384 + n * 128 + (((k >> 3) ^ (n & 7)) << 3) + (k & 7)] = f2bf(W2[j]);
    } else {
        int j = t - 32768;                           // j = k*1024 + n
        int k = j >> 10, n = j & 1023;
        int tile = n >> 7, nl = n & 127;
        ws[32768 + tile * 16384 + nl * 128 + (((k >> 3) ^ (nl & 7)) << 3) + (k & 7)]
            = f2bf(W3[j]);
    }
}

__global__ __launch_bounds__(256, 2)
void fused_edge_mlp(const float* __restrict__ edge, const float* __restrict__ x,
                    const float* __restrict__ b1, const float* __restrict__ g1,
                    const float* __restrict__ be1,
                    const float* __restrict__ b2, const float* __restrict__ g2,
                    const float* __restrict__ be2,
                    const float* __restrict__ b3,
                    const unsigned short* __restrict__ wsW,
                    float* __restrict__ out) {
    // sA: bf16 [128 edge-rows][128 k], 256B/row, XOR-swizzled. edge->h1->h2.
    // Rows wave-private. Reused as sOut[128][OPITCH] fp32 during layer 3.
    __shared__ __align__(16) unsigned char sA[TM * 256];       // 32 KB
    // sW: bf16 W^T tile [128 n][128 k], swizzled; filled by global_load_lds.
    __shared__ __align__(16) unsigned char sW[128 * 256];      // 32 KB
    float* sOut = (float*)sA;

    const int t    = threadIdx.x;
    const int lane = t & 63;
    const int w    = t >> 6;
    const int e0   = blockIdx.x * TM;
    const int erow = w * 32;          // wave's first local edge row
    const int mrow = lane & 15;
    const int hi   = lane >> 4;
    const int swzl = (mrow & 7) << 4;

    // ---- W staging: async DMA, wave-uniform LDS base + lane*16 ----
    auto stageW = [&](const unsigned short* srcW) {
        int wbase = w * 64;
#pragma unroll
        for (int i = 0; i < 8; i++) {
            int base = wbase + i * 256;              // 2048 x 16B chunks total
            gl_lds16(srcW + (size_t)(base + lane) * 8, sW + (size_t)base * 16);
        }
    };

    // ---- MFMA pass (layers 1/2): C[n=128][e=32] += W(sW)^T . h(sA) ----
    auto runMM = [&](f32x4 (&acc)[2][8]) {
#pragma unroll
        for (int kk = 0; kk < 4; kk++) {
            int kb = (kk * 64 + hi * 16) ^ swzl;
            bf16x8 bA = *(const bf16x8*)(sA + (erow + mrow) * 256 + kb);
            bf16x8 bB = *(const bf16x8*)(sA + (erow + 16 + mrow) * 256 + kb);
#pragma unroll
            for (int fn = 0; fn < 8; fn++) {
                bf16x8 a = *(const bf16x8*)(sW + (fn * 16 + mrow) * 256 + kb);
                acc[0][fn] = __builtin_amdgcn_mfma_f32_16x16x32_bf16(a, bA, acc[0][fn], 0, 0, 0);
                acc[1][fn] = __builtin_amdgcn_mfma_f32_16x16x32_bf16(a, bB, acc[1][fn], 0, 0, 0);
            }
        }
    };
    // C/D: col(e-local-16) = mrow, feature n = fn*16 + hi*4 + rr.

    // ---- layer-3 MFMA with h2 B-frags cached in registers ----
    auto runMM3 = [&](f32x4 (&acc)[2][8], const bf16x8 (&bc)[2][4]) {
#pragma unroll
        for (int kk = 0; kk < 4; kk++) {
            int kb = (kk * 64 + hi * 16) ^ swzl;
#pragma unroll
            for (int fn = 0; fn < 8; fn++) {
                bf16x8 a = *(const bf16x8*)(sW + (fn * 16 + mrow) * 256 + kb);
                acc[0][fn] = __builtin_amdgcn_mfma_f32_16x16x32_bf16(a, bc[0][kk], acc[0][fn], 0, 0, 0);
                acc[1][fn] = __builtin_amdgcn_mfma_f32_16x16x32_bf16(a, bc[1][kk], acc[1][fn], 0, 0, 0);
            }
        }
    };

    f32x4 xq[2][2];                   // x[e][b*16 + hi*4 .. +4]

    // ---- LN + exact GELU per edge-col (R5/R6 verbatim, verified) ----
    auto lnGelu = [&](f32x4 (&acc)[2][8], const float* bb, const float* gg,
                      const float* ee) {
#pragma unroll
        for (int fe = 0; fe < 2; fe++) {
            float hv[8][4];
            float s = 0.f, s2 = 0.f;
#pragma unroll
            for (int fn = 0; fn < 8; fn++) {
                f32x4 b4 = *(const f32x4*)(bb + fn * 16 + hi * 4);
#pragma unroll
                for (int rr = 0; rr < 4; rr++) {
                    float v = acc[fe][fn][rr] + b4[rr];
                    hv[fn][rr] = v; s += v; s2 += v * v;
                }
            }
            s  += __shfl_xor(s, 16);  s  += __shfl_xor(s, 32);
            s2 += __shfl_xor(s2, 16); s2 += __shfl_xor(s2, 32);
            float mean = s * (1.0f / 128.0f);
            float rsv  = rsqrtf(s2 * (1.0f / 128.0f) - mean * mean + 1e-5f);
            int row = erow + fe * 16 + mrow;         // row&7 == mrow&7
#pragma unroll
            for (int fn = 0; fn < 8; fn++) {
                f32x4 g4 = *(const f32x4*)(gg + fn * 16 + hi * 4);
                f32x4 e4 = *(const f32x4*)(ee + fn * 16 + hi * 4);
                ushort4v u;
#pragma unroll
                for (int rr = 0; rr < 4; rr++) {
                    float f = (hv[fn][rr] - mean) * rsv * g4[rr] + e4[rr];
                    f = 0.5f * f * (1.0f + erff(f * 0.70710678118f));   // exact GELU
                    u[rr] = f2bf(f);
                }
                *(ushort4v*)(sA + row * 256 + ((fn * 32 + hi * 8) ^ swzl)) = u;
            }
        }
    };

    // ---- layer-3 GEMV (R5 math, verified); result -> sOut, aligned f32x4 ----
    auto gemv = [&](f32x4 (&acc)[2][8], int c) {
        f32x4 b3q[8];
#pragma unroll
        for (int fn = 0; fn < 8; fn++)
            b3q[fn] = *(const f32x4*)(b3 + c * 128 + fn * 16 + hi * 4);
#pragma unroll
        for (int fe = 0; fe < 2; fe++) {
            f32x4 pv;
#pragma unroll
            for (int o = 0; o < 4; o++) {
                float p = 0.f;
#pragma unroll
                for (int rr = 0; rr < 4; rr++) {
                    p += (acc[fe][2*o][rr]   + b3q[2*o][rr])   * xq[fe][0][rr];
                    p += (acc[fe][2*o+1][rr] + b3q[2*o+1][rr]) * xq[fe][1][rr];
                }
                p += __shfl_xor(p, 16);              // reduce over hi
                p += __shfl_xor(p, 32);
                pv[o] = p;
            }
            if (hi == (c >> 1))                      // owning lane writes 16B
                *(f32x4*)(sOut + (erow + fe * 16 + mrow) * OPITCH + c * 4) = pv;
        }
    };

    // ================= prologue =================
    stageW(wsW);                                     // W1 DMA (overlaps below)
#pragma unroll
    for (int i = 0; i < 8; i++) {                    // edge -> sA (verified)
        int c = lane + i * 64;                       // wave-private rows
        int r = erow + (c >> 4), kg = c & 15;
        const float* src = edge + (size_t)(e0 + r) * 128 + kg * 8;
        float4 v0 = *(const float4*)src, v1 = *(const float4*)(src + 4);
        ushort8 u;
        u[0] = f2bf(v0.x); u[1] = f2bf(v0.y); u[2] = f2bf(v0.z); u[3] = f2bf(v0.w);
        u[4] = f2bf(v1.x); u[5] = f2bf(v1.y); u[6] = f2bf(v1.z); u[7] = f2bf(v1.w);
        *(ushort8*)(sA + r * 256 + ((kg * 16) ^ ((r & 7) << 4))) = u;
    }
#pragma unroll
    for (int fe = 0; fe < 2; fe++)
#pragma unroll
        for (int b = 0; b < 2; b++)
            xq[fe][b] = *(const f32x4*)(
                x + (size_t)(e0 + erow + fe * 16 + mrow) * 32 + b * 16 + hi * 4);
    __syncthreads();                                 // W1 in LDS (vmcnt drained)

    f32x4 acc[2][8];
    const f32x4 zz = {0.f, 0.f, 0.f, 0.f};

    // ================= layer 1 =================
#pragma unroll
    for (int i = 0; i < 2; i++) for (int j = 0; j < 8; j++) acc[i][j] = zz;
    runMM(acc);                       // reads sW(W1) + own sA rows
    __syncthreads();                  // all waves done reading sW(W1)
    stageW(wsW + 16384);              // W2 DMA (overlaps lnGelu VALU)
    lnGelu(acc, b1, g1, be1);         // own sA rows <- h1
    __syncthreads();                  // W2 ready

    // ================= layer 2 =================
#pragma unroll
    for (int i = 0; i < 2; i++) for (int j = 0; j < 8; j++) acc[i][j] = zz;
    runMM(acc);
    __syncthreads();
    stageW(wsW + 32768);              // W3 chunk 0 DMA
    lnGelu(acc, b2, g2, be2);         // own sA rows <- h2
    __syncthreads();                  // W3c0 ready

    // ---- cache h2 B-frags in registers (sA then reused as sOut) ----
    bf16x8 bc[2][4];
#pragma unroll
    for (int kk = 0; kk < 4; kk++) {
        int kb = (kk * 64 + hi * 16) ^ swzl;
        bc[0][kk] = *(const bf16x8*)(sA + (erow + mrow) * 256 + kb);
        bc[1][kk] = *(const bf16x8*)(sA + (erow + 16 + mrow) * 256 + kb);
    }

    // ================= layer 3: 8 chunks of 128 features =================
    for (int c = 0; c < 8; c++) {
#pragma unroll
        for (int i = 0; i < 2; i++) for (int j = 0; j < 8; j++) acc[i][j] = zz;
        runMM3(acc, bc);              // reads sW(W3c) + bc regs
        __syncthreads();              // sW(W3c) reads done
        if (c < 7) stageW(wsW + 32768 + (size_t)(c + 1) * 16384);  // async DMA
        gemv(acc, c);                 // VALU + shfl + sOut (under DMA shadow)
        if (c < 7) __syncthreads();   // DMA drained
    }

    // ================= epilogue: coalesced output stores =================
#pragma unroll
    for (int fe = 0; fe < 2; fe++) {
        int e_l = erow + fe * 16 + mrow;
        f32x4 v0 = *(const f32x4*)(sOut + e_l * OPITCH + hi * 8);
        f32x4 v1 = *(const f32x4*)(sOut + e_l * OPITCH + hi * 8 + 4);
        *(f32x4*)(out + (size_t)(e0 + e_l) * 32 + hi * 8)     = v0;
        *(f32x4*)(out + (size_t)(e0 + e_l) * 32 + hi * 8 + 4) = v1;
    }
}

extern "C" void kernel_launch(void* const* d_in, const int* in_sizes, int n_in,
                              void* d_out, int out_size, void* d_ws, size_t ws_size,
                              hipStream_t stream) {
    const float* x    = (const float*)d_in[0];
    const float* edge = (const float*)d_in[1];
    const float* W1   = (const float*)d_in[2];
    const float* b1   = (const float*)d_in[3];
    const float* g1   = (const float*)d_in[4];
    const float* be1  = (const float*)d_in[5];
    const float* W2   = (const float*)d_in[6];
    const float* b2   = (const float*)d_in[7];
    const float* g2   = (const float*)d_in[8];
    const float* be2  = (const float*)d_in[9];
    const float* W3   = (const float*)d_in[10];
    const float* b3   = (const float*)d_in[11];
    unsigned short* wsW = (unsigned short*)d_ws;     // 320 KB pre-swizzled W^T bf16
    float* outp = (float*)d_out;

    prep_weights<<<640, 256, 0, stream>>>(W1, W2, W3, wsW);
    fused_edge_mlp<<<N_EDGES / TM, 256, 0, stream>>>(
        edge, x, b1, g1, be1, b2, g2, be2, b3, wsW, outp);
}